// Round 5
// baseline (108.497 us; speedup 1.0000x reference)
//
#include <hip/hip_runtime.h>
#include <hip/hip_bf16.h>

// ConvEncoder: emb gather (padding_idx=0) + WIN=5 im2col + Linear(640->128) + exact GELU
// dtypes per reference: x int32, emb/W/b float32, OUTPUT float32.
// GEMM view: C[32768,128] = A[32768,640] * W^T, W is (128,640) row-major.
// A[m, win*128+e] = emb_table[x[b, s+win-2], e]  (zero when s+win-2 OOB; token 0 row IS zero)
// fp32 inputs are converted RNE->bf16 at LDS-staging time; MFMA in bf16, fp32 accum, fp32 out.

#define EMB   128
#define WIN   5
#define OUTC  128
#define SEQ   2048
#define KTOT  640
#define MTILE 128

// LDS strides (elements), padded so 16-row-strided ds_read_b128 is only 2-way bank-aliased (free)
#define EMB_STRIDE 136   // 128 + 8 -> 272 B rows
#define W_STRIDE   72    // 64 + 8  -> 144 B rows

typedef __bf16  bf16x8 __attribute__((ext_vector_type(8)));
typedef float   f32x4  __attribute__((ext_vector_type(4)));
typedef ushort  u16x8  __attribute__((ext_vector_type(8)));

__device__ inline ushort f2bf(float f) {
    __bf16 h = (__bf16)f;                     // RNE convert
    return __builtin_bit_cast(ushort, h);
}

__device__ inline u16x8 cvt8(const float* p) {
    const float4 v0 = *(const float4*)p;
    const float4 v1 = *(const float4*)(p + 4);
    u16x8 o;
    o[0] = f2bf(v0.x); o[1] = f2bf(v0.y); o[2] = f2bf(v0.z); o[3] = f2bf(v0.w);
    o[4] = f2bf(v1.x); o[5] = f2bf(v1.y); o[6] = f2bf(v1.z); o[7] = f2bf(v1.w);
    return o;
}

__global__ __launch_bounds__(256) void conv_encoder_kernel(
    const int* __restrict__ x,                 // (16, 2048) int32
    const float* __restrict__ emb,             // (50257, 128) f32, row 0 is zero
    const float* __restrict__ W,               // (128, 640) f32
    const float* __restrict__ bias,            // (128,) f32
    float* __restrict__ out)                   // (32768, 128) f32
{
    __shared__ ushort sEmb[(MTILE + WIN - 1) * EMB_STRIDE]; // 132 rows: s0-2 .. s0+129
    __shared__ ushort sW[OUTC * W_STRIDE];                  // 128 rows x 64 k-slice

    const int tid = threadIdx.x;
    const int bid = blockIdx.x;
    const int m0  = bid * MTILE;       // global row base
    const int bb  = m0 >> 11;          // batch index (2048 per batch)
    const int s0  = m0 & (SEQ - 1);    // seq base within batch

    // ---- Stage embeddings for this tile (+halo): 132 rows x 128 elems, cvt f32->bf16 ----
    {
        const int xbase = bb * SEQ;
        for (int idx = tid; idx < (MTILE + WIN - 1) * 16; idx += 256) {
            const int r = idx >> 4, c = idx & 15;          // c = 8-elem chunk
            const int s = s0 - 2 + r;
            const int tok = (s >= 0 && s < SEQ) ? x[xbase + s] : 0; // token 0 row is zero
            const u16x8 v = cvt8(emb + (size_t)tok * EMB + c * 8);
            *(u16x8*)(&sEmb[r * EMB_STRIDE + c * 8]) = v;
        }
    }

    const int lane = tid & 63;
    const int wv   = tid >> 6;
    const int qr   = (wv >> 1) * 64;   // wave row quadrant
    const int qc   = (wv & 1) * 64;    // wave col quadrant
    const int lr   = lane & 15;        // m (A) / n (B) / col (C) within 16-tile
    const int lk8  = (lane >> 4) * 8;  // k sub-offset

    f32x4 acc[4][4];
    #pragma unroll
    for (int i = 0; i < 4; ++i)
        #pragma unroll
        for (int j = 0; j < 4; ++j)
            acc[i][j] = (f32x4){0.f, 0.f, 0.f, 0.f};

    // ---- K loop: 5 windows x 2 half-slices (64 k each) staged through sW ----
    for (int stage = 0; stage < 2 * WIN; ++stage) {
        const int win = stage >> 1;
        const int kh  = (stage & 1) * 64;   // k offset within this window's 128

        __syncthreads();   // previous stage's sW reads done (also covers sEmb staging on stage 0)
        for (int idx = tid; idx < OUTC * 8; idx += 256) {
            const int r = idx >> 3, c = idx & 7;           // c = 8-elem chunk of the 64-slice
            const u16x8 v = cvt8(W + (size_t)r * KTOT + win * EMB + kh + c * 8);
            *(u16x8*)(&sW[r * W_STRIDE + c * 8]) = v;
        }
        __syncthreads();

        #pragma unroll
        for (int kc = 0; kc < 2; ++kc) {
            const int eA = kh + kc * 32 + lk8;   // col within sEmb row
            const int eB = kc * 32 + lk8;        // col within sW row
            bf16x8 afr[4], bfr[4];
            #pragma unroll
            for (int i = 0; i < 4; ++i)
                afr[i] = *(const bf16x8*)(&sEmb[(qr + i * 16 + lr + win) * EMB_STRIDE + eA]);
            #pragma unroll
            for (int j = 0; j < 4; ++j)
                bfr[j] = *(const bf16x8*)(&sW[(qc + j * 16 + lr) * W_STRIDE + eB]);
            #pragma unroll
            for (int i = 0; i < 4; ++i)
                #pragma unroll
                for (int j = 0; j < 4; ++j)
                    acc[i][j] = __builtin_amdgcn_mfma_f32_16x16x32_bf16(afr[i], bfr[j], acc[i][j], 0, 0, 0);
        }
    }

    // ---- Epilogue: bias + exact GELU + fp32 store ----
    float bj[4];
    #pragma unroll
    for (int j = 0; j < 4; ++j)
        bj[j] = bias[qc + j * 16 + lr];

    const int rbase = (lane >> 4) * 4;
    #pragma unroll
    for (int i = 0; i < 4; ++i) {
        #pragma unroll
        for (int j = 0; j < 4; ++j) {
            const int col = qc + j * 16 + lr;
            #pragma unroll
            for (int r = 0; r < 4; ++r) {
                const int row = m0 + qr + i * 16 + rbase + r;
                const float y = acc[i][j][r] + bj[j];
                const float g = 0.5f * y * (1.0f + erff(y * 0.70710678118654752f));
                out[(size_t)row * OUTC + col] = g;
            }
        }
    }
}

extern "C" void kernel_launch(void* const* d_in, const int* in_sizes, int n_in,
                              void* d_out, int out_size, void* d_ws, size_t ws_size,
                              hipStream_t stream) {
    (void)in_sizes; (void)n_in; (void)d_ws; (void)ws_size; (void)out_size;
    const int* x              = (const int*)d_in[0];
    const float* emb          = (const float*)d_in[1];
    const float* Wm           = (const float*)d_in[2];
    const float* bias         = (const float*)d_in[3];
    float* out                = (float*)d_out;

    dim3 grid(32768 / MTILE);   // 256 blocks
    dim3 block(256);
    hipLaunchKernelGGL(conv_encoder_kernel, grid, block, 0, stream, x, emb, Wm, bias, out);
}

// Round 7
// 94.628 us; speedup vs baseline: 1.1466x; 1.1466x over previous
//
#include <hip/hip_runtime.h>
#include <hip/hip_bf16.h>

// ConvEncoder: emb gather (padding_idx=0) + WIN=5 im2col + Linear(640->128) + exact GELU
// dtypes: x int32, emb/W/b float32, OUTPUT float32.
// GEMM view: C[32768,128] = A[32768,640] * W^T, W (128,640) row-major.
// A[m, win*128+e] = emb[x[b, s+win-2], e]; OOB -> token 0 whose row is zero.
// Round 6: 64x64 tiles, grid 1024 (4 blocks/CU, 16 waves/CU), 5 window-stages
// with register-prefetched W. bf16 MFMA, fp32 accum, fp32 out.

#define EMB   128
#define WIN   5
#define OUTC  128
#define SEQ   2048
#define KTOT  640
#define MTILE 64
#define NTILE 64

#define EMB_STRIDE 136   // 128+8 elems; 272 B rows (16B-aligned, bank-stride 4 -> 2-way, free)
#define SW_STRIDE  136

typedef __bf16  bf16x8 __attribute__((ext_vector_type(8)));
typedef float   f32x4  __attribute__((ext_vector_type(4)));
typedef ushort  u16x8  __attribute__((ext_vector_type(8)));

__device__ inline ushort f2bf(float f) {
    __bf16 h = (__bf16)f;  // RNE
    return __builtin_bit_cast(ushort, h);
}

__device__ inline u16x8 cvt8v(float4 v0, float4 v1) {
    u16x8 o;
    o[0] = f2bf(v0.x); o[1] = f2bf(v0.y); o[2] = f2bf(v0.z); o[3] = f2bf(v0.w);
    o[4] = f2bf(v1.x); o[5] = f2bf(v1.y); o[6] = f2bf(v1.z); o[7] = f2bf(v1.w);
    return o;
}

__global__ __launch_bounds__(256, 4) void conv_encoder_kernel(
    const int* __restrict__ x,                 // (16, 2048)
    const float* __restrict__ emb,             // (50257, 128), row 0 zero
    const float* __restrict__ W,               // (128, 640)
    const float* __restrict__ bias,            // (128,)
    float* __restrict__ out)                   // (32768, 128)
{
    __shared__ ushort sEmb[(MTILE + WIN - 1) * EMB_STRIDE]; // 68 rows
    __shared__ ushort sW[NTILE * SW_STRIDE];                // 64 rows x 128-k window slice

    const int tid = threadIdx.x;
    const int bid = blockIdx.x;
    const int mi  = bid >> 1;          // M-tile index (0..511)
    const int n0  = (bid & 1) * NTILE; // N half
    const int m0  = mi * MTILE;
    const int bb  = m0 >> 11;          // batch
    const int s0  = m0 & (SEQ - 1);    // seq base

    // ---- Stage embeddings (68 rows x 128 elems), cvt f32->bf16 ----
    {
        const int xbase = bb * SEQ;
        for (int idx = tid; idx < (MTILE + WIN - 1) * 16; idx += 256) {
            const int r = idx >> 4, c = idx & 15;
            const int s = s0 - 2 + r;
            const int tok = (s >= 0 && s < SEQ) ? x[xbase + s] : 0;
            const float* p = emb + (size_t)tok * EMB + c * 8;
            *(u16x8*)(&sEmb[r * EMB_STRIDE + c * 8]) =
                cvt8v(*(const float4*)p, *(const float4*)(p + 4));
        }
    }

    const int lane = tid & 63;
    const int wv   = tid >> 6;
    const int qr   = (wv >> 1) * 32;   // wave row base within block
    const int qc   = (wv & 1) * 32;    // wave col base within block
    const int lr   = lane & 15;
    const int lk8  = (lane >> 4) * 8;

    f32x4 acc[2][2];
    #pragma unroll
    for (int i = 0; i < 2; ++i)
        #pragma unroll
        for (int j = 0; j < 2; ++j)
            acc[i][j] = (f32x4){0.f, 0.f, 0.f, 0.f};

    // ---- Prefetch window 0 of W into regs (64 rows x 128 k = 1024 chunks, 4/thread) ----
    float4 preA[4], preB[4];
    #pragma unroll
    for (int t = 0; t < 4; ++t) {
        const int idx = tid + t * 256;
        const int r = idx >> 4, c = idx & 15;
        const float* p = W + (size_t)(n0 + r) * KTOT + c * 8;
        preA[t] = *(const float4*)p;
        preB[t] = *(const float4*)(p + 4);
    }

    for (int win = 0; win < WIN; ++win) {
        __syncthreads();   // prior sW reads done (stage 0: pairs with 2nd barrier for sEmb)
        #pragma unroll
        for (int t = 0; t < 4; ++t) {
            const int idx = tid + t * 256;
            const int r = idx >> 4, c = idx & 15;
            *(u16x8*)(&sW[r * SW_STRIDE + c * 8]) = cvt8v(preA[t], preB[t]);
        }
        if (win + 1 < WIN) {   // issue next window's loads; fly during compute
            #pragma unroll
            for (int t = 0; t < 4; ++t) {
                const int idx = tid + t * 256;
                const int r = idx >> 4, c = idx & 15;
                const float* p = W + (size_t)(n0 + r) * KTOT + (win + 1) * EMB + c * 8;
                preA[t] = *(const float4*)p;
                preB[t] = *(const float4*)(p + 4);
            }
        }
        __syncthreads();

        #pragma unroll
        for (int kc = 0; kc < 4; ++kc) {
            const int e = kc * 32 + lk8;
            bf16x8 afr[2], bfr[2];
            #pragma unroll
            for (int i = 0; i < 2; ++i)
                afr[i] = *(const bf16x8*)(&sEmb[(qr + i * 16 + lr + win) * EMB_STRIDE + e]);
            #pragma unroll
            for (int j = 0; j < 2; ++j)
                bfr[j] = *(const bf16x8*)(&sW[(qc + j * 16 + lr) * SW_STRIDE + e]);
            #pragma unroll
            for (int i = 0; i < 2; ++i)
                #pragma unroll
                for (int j = 0; j < 2; ++j)
                    acc[i][j] = __builtin_amdgcn_mfma_f32_16x16x32_bf16(afr[i], bfr[j], acc[i][j], 0, 0, 0);
        }
    }

    // ---- Epilogue: bias + exact GELU + fp32 store ----
    float bj[2];
    #pragma unroll
    for (int j = 0; j < 2; ++j)
        bj[j] = bias[n0 + qc + j * 16 + lr];

    const int rbase = (lane >> 4) * 4;
    #pragma unroll
    for (int i = 0; i < 2; ++i) {
        #pragma unroll
        for (int j = 0; j < 2; ++j) {
            const int col = n0 + qc + j * 16 + lr;
            #pragma unroll
            for (int r = 0; r < 4; ++r) {
                const int row = m0 + qr + i * 16 + rbase + r;
                const float y = acc[i][j][r] + bj[j];
                const float g = 0.5f * y * (1.0f + erff(y * 0.70710678118654752f));
                out[(size_t)row * OUTC + col] = g;
            }
        }
    }
}

extern "C" void kernel_launch(void* const* d_in, const int* in_sizes, int n_in,
                              void* d_out, int out_size, void* d_ws, size_t ws_size,
                              hipStream_t stream) {
    (void)in_sizes; (void)n_in; (void)d_ws; (void)ws_size; (void)out_size;
    const int* x        = (const int*)d_in[0];
    const float* emb    = (const float*)d_in[1];
    const float* Wm     = (const float*)d_in[2];
    const float* bias   = (const float*)d_in[3];
    float* out          = (float*)d_out;

    dim3 grid((32768 / MTILE) * (OUTC / NTILE));  // 1024 blocks -> 4/CU
    dim3 block(256);
    hipLaunchKernelGGL(conv_encoder_kernel, grid, block, 0, stream, x, emb, Wm, bias, out);
}

// Round 8
// 93.289 us; speedup vs baseline: 1.1630x; 1.0144x over previous
//
#include <hip/hip_runtime.h>
#include <hip/hip_bf16.h>

// ConvEncoder: emb gather (padding_idx=0) + WIN=5 im2col + Linear(640->128) + exact GELU
// dtypes: x int32, emb/W/b float32, OUTPUT float32.
// GEMM view: C[32768,128] = A[32768,640] * W^T, W (128,640) row-major.
// Round 8: same 64x64 tiling as R6 (grid 1024 = 4 blocks/CU, 16 waves/CU), but:
//  - next-window W loads issued AFTER the 2nd barrier (compiler emits vmcnt(0)
//    before s_barrier, so issuing before it drained the prefetch = R7's stall)
//  - grid (512,2): N-pair blocks land on the same XCD (%8) for L2 gather reuse
//  - window-0 W loads issued before the gather chain.

#define EMB   128
#define WIN   5
#define OUTC  128
#define SEQ   2048
#define KTOT  640
#define MTILE 64
#define NTILE 64

#define EMB_STRIDE 136   // 128+8 elems; 16B-aligned rows, 2-way bank alias (free)
#define SW_STRIDE  136

typedef __bf16  bf16x8 __attribute__((ext_vector_type(8)));
typedef float   f32x4  __attribute__((ext_vector_type(4)));
typedef ushort  u16x8  __attribute__((ext_vector_type(8)));

__device__ inline ushort f2bf(float f) {
    __bf16 h = (__bf16)f;  // RNE
    return __builtin_bit_cast(ushort, h);
}

__device__ inline u16x8 cvt8v(float4 v0, float4 v1) {
    u16x8 o;
    o[0] = f2bf(v0.x); o[1] = f2bf(v0.y); o[2] = f2bf(v0.z); o[3] = f2bf(v0.w);
    o[4] = f2bf(v1.x); o[5] = f2bf(v1.y); o[6] = f2bf(v1.z); o[7] = f2bf(v1.w);
    return o;
}

__global__ __launch_bounds__(256, 4) void conv_encoder_kernel(
    const int* __restrict__ x,                 // (16, 2048)
    const float* __restrict__ emb,             // (50257, 128), row 0 zero
    const float* __restrict__ W,               // (128, 640)
    const float* __restrict__ bias,            // (128,)
    float* __restrict__ out)                   // (32768, 128)
{
    __shared__ ushort sEmb[(MTILE + WIN - 1) * EMB_STRIDE]; // 68 rows
    __shared__ ushort sW[NTILE * SW_STRIDE];                // 64 rows x 128-k window slice

    const int tid = threadIdx.x;
    const int mi  = blockIdx.x;            // M-tile (0..511)
    const int n0  = blockIdx.y * NTILE;    // N half; pair is 512 blocks apart -> same XCD
    const int m0  = mi * MTILE;
    const int bb  = m0 >> 11;              // batch
    const int s0  = m0 & (SEQ - 1);        // seq base

    // ---- Issue window-0 W prefetch FIRST (independent of the gather chain) ----
    float4 preA[4], preB[4];
    #pragma unroll
    for (int t = 0; t < 4; ++t) {
        const int idx = tid + t * 256;
        const int r = idx >> 4, c = idx & 15;
        const float* p = W + (size_t)(n0 + r) * KTOT + c * 8;
        preA[t] = *(const float4*)p;
        preB[t] = *(const float4*)(p + 4);
    }

    // ---- Stage embeddings (68 rows x 128 elems), cvt f32->bf16 ----
    {
        const int xbase = bb * SEQ;
        for (int idx = tid; idx < (MTILE + WIN - 1) * 16; idx += 256) {
            const int r = idx >> 4, c = idx & 15;
            const int s = s0 - 2 + r;
            const int tok = (s >= 0 && s < SEQ) ? x[xbase + s] : 0;
            const float* p = emb + (size_t)tok * EMB + c * 8;
            *(u16x8*)(&sEmb[r * EMB_STRIDE + c * 8]) =
                cvt8v(*(const float4*)p, *(const float4*)(p + 4));
        }
    }

    const int lane = tid & 63;
    const int wv   = tid >> 6;
    const int qr   = (wv >> 1) * 32;   // wave row base within block
    const int qc   = (wv & 1) * 32;    // wave col base within block
    const int lr   = lane & 15;
    const int lk8  = (lane >> 4) * 8;

    f32x4 acc[2][2];
    #pragma unroll
    for (int i = 0; i < 2; ++i)
        #pragma unroll
        for (int j = 0; j < 2; ++j)
            acc[i][j] = (f32x4){0.f, 0.f, 0.f, 0.f};

    for (int win = 0; win < WIN; ++win) {
        __syncthreads();   // A: prior sW reads done (iter 0: makes sEmb staging visible)
        #pragma unroll
        for (int t = 0; t < 4; ++t) {
            const int idx = tid + t * 256;
            const int r = idx >> 4, c = idx & 15;
            *(u16x8*)(&sW[r * SW_STRIDE + c * 8]) = cvt8v(preA[t], preB[t]);
        }
        __syncthreads();   // B: sW visible

        // Issue next window's loads AFTER barrier B: they fly through the MFMA
        // region and are only drained at next iteration's barrier A (post-compute).
        if (win + 1 < WIN) {
            #pragma unroll
            for (int t = 0; t < 4; ++t) {
                const int idx = tid + t * 256;
                const int r = idx >> 4, c = idx & 15;
                const float* p = W + (size_t)(n0 + r) * KTOT + (win + 1) * EMB + c * 8;
                preA[t] = *(const float4*)p;
                preB[t] = *(const float4*)(p + 4);
            }
        }

        #pragma unroll
        for (int kc = 0; kc < 4; ++kc) {
            const int e = kc * 32 + lk8;
            bf16x8 afr[2], bfr[2];
            #pragma unroll
            for (int i = 0; i < 2; ++i)
                afr[i] = *(const bf16x8*)(&sEmb[(qr + i * 16 + lr + win) * EMB_STRIDE + e]);
            #pragma unroll
            for (int j = 0; j < 2; ++j)
                bfr[j] = *(const bf16x8*)(&sW[(qc + j * 16 + lr) * SW_STRIDE + e]);
            #pragma unroll
            for (int i = 0; i < 2; ++i)
                #pragma unroll
                for (int j = 0; j < 2; ++j)
                    acc[i][j] = __builtin_amdgcn_mfma_f32_16x16x32_bf16(afr[i], bfr[j], acc[i][j], 0, 0, 0);
        }
    }

    // ---- Epilogue: bias + exact GELU + fp32 store ----
    float bj[2];
    #pragma unroll
    for (int j = 0; j < 2; ++j)
        bj[j] = bias[n0 + qc + j * 16 + lr];

    const int rbase = (lane >> 4) * 4;
    #pragma unroll
    for (int i = 0; i < 2; ++i) {
        #pragma unroll
        for (int j = 0; j < 2; ++j) {
            const int col = n0 + qc + j * 16 + lr;
            #pragma unroll
            for (int r = 0; r < 4; ++r) {
                const int row = m0 + qr + i * 16 + rbase + r;
                const float y = acc[i][j][r] + bj[j];
                const float g = 0.5f * y * (1.0f + erff(y * 0.70710678118654752f));
                out[(size_t)row * OUTC + col] = g;
            }
        }
    }
}

extern "C" void kernel_launch(void* const* d_in, const int* in_sizes, int n_in,
                              void* d_out, int out_size, void* d_ws, size_t ws_size,
                              hipStream_t stream) {
    (void)in_sizes; (void)n_in; (void)d_ws; (void)ws_size; (void)out_size;
    const int* x        = (const int*)d_in[0];
    const float* emb    = (const float*)d_in[1];
    const float* Wm     = (const float*)d_in[2];
    const float* bias   = (const float*)d_in[3];
    float* out          = (float*)d_out;

    dim3 grid(32768 / MTILE, OUTC / NTILE);   // (512, 2) = 1024 blocks -> 4/CU
    dim3 block(256);
    hipLaunchKernelGGL(conv_encoder_kernel, grid, block, 0, stream, x, emb, Wm, bias, out);
}